// Round 5
// baseline (202.730 us; speedup 1.0000x reference)
//
#include <hip/hip_runtime.h>
#include <math.h>

#define EMB 512
#define NH 8
#define HD 64
#define BB 2
#define SS 1024
#define ROWS (BB * SS) /* 2048 */

typedef __attribute__((ext_vector_type(8))) short bhalf8;
typedef __attribute__((ext_vector_type(4))) float f32x4;
typedef __attribute__((ext_vector_type(8))) unsigned short us8;
typedef unsigned short ushort_t;

__device__ __forceinline__ unsigned short f2bf(float x) {
  unsigned u = __float_as_uint(x);
  u = (u + 0x7FFFu + ((u >> 16) & 1u)) >> 16;
  return (unsigned short)u;
}
__device__ __forceinline__ float bf2f(unsigned short v) {
  return __uint_as_float(((unsigned)v) << 16);
}
__device__ __forceinline__ float fast_tanh(float x) {
  x = fminf(15.f, fmaxf(-15.f, x));
  const float e = __expf(2.f * x);
  return (e - 1.f) / (e + 1.f);
}

// ============================================================
// prep: converts + weight transposes + zero d_out/lsum + zero qp row 1023
// ============================================================
__global__ __launch_bounds__(256) void prep_kernel(
    const float* __restrict__ f_emb, const float* __restrict__ gpe,
    const float* __restrict__ Wu, const float* __restrict__ Wq,
    const float* __restrict__ Wkv, const float* __restrict__ Wp,
    ushort_t* __restrict__ f16emb, ushort_t* __restrict__ gpe16,
    ushort_t* __restrict__ WtAll, ushort_t* __restrict__ WpT,
    float* __restrict__ outZ, float* __restrict__ lsumZ,
    ushort_t* __restrict__ Qcomb) {
  __shared__ float sT[64 * 65];
  const int bid = blockIdx.x, tid = threadIdx.x;
  if (bid < 512) {  // f_emb -> bf16 (1M elems)
    const int i = (bid * 256 + tid) * 8;
    const float4 a = *(const float4*)&f_emb[i];
    const float4 b = *(const float4*)&f_emb[i + 4];
    us8 o;
    o[0] = f2bf(a.x); o[1] = f2bf(a.y); o[2] = f2bf(a.z); o[3] = f2bf(a.w);
    o[4] = f2bf(b.x); o[5] = f2bf(b.y); o[6] = f2bf(b.z); o[7] = f2bf(b.w);
    *(us8*)&f16emb[i] = o;
  } else if (bid < 640) {  // gpe -> bf16 (262144 elems)
    const int i = ((bid - 512) * 256 + tid) * 8;
    const float4 a = *(const float4*)&gpe[i];
    const float4 b = *(const float4*)&gpe[i + 4];
    us8 o;
    o[0] = f2bf(a.x); o[1] = f2bf(a.y); o[2] = f2bf(a.z); o[3] = f2bf(a.w);
    o[4] = f2bf(b.x); o[5] = f2bf(b.y); o[6] = f2bf(b.z); o[7] = f2bf(b.w);
    *(us8*)&gpe16[i] = o;
  } else if (bid < 912) {  // weight transpose+convert
    int z = bid - 640;
    const float* src;
    ushort_t* dst;
    int K, N, n0, k0;
    if (z < 64) {
      src = Wu; dst = WtAll; K = 512; N = 512;
      n0 = (z & 7) * 64; k0 = (z >> 3) * 64;
    } else if (z < 128) {
      z -= 64; src = Wq; dst = WtAll + 512 * 512; K = 512; N = 512;
      n0 = (z & 7) * 64; k0 = (z >> 3) * 64;
    } else if (z < 256) {
      z -= 128; src = Wkv; dst = WtAll + 1024 * 512; K = 512; N = 1024;
      n0 = (z & 15) * 64; k0 = (z >> 4) * 64;
    } else {
      z -= 256; src = Wp; dst = WpT; K = 128; N = 512;
      n0 = (z & 7) * 64; k0 = (z >> 3) * 64;
    }
#pragma unroll
    for (int i = 0; i < 4; ++i) {
      const int idx = i * 256 + tid;
      const int r = idx >> 4, c4 = (idx & 15) * 4;
      const float4 v = *(const float4*)&src[(size_t)(k0 + r) * N + n0 + c4];
      sT[(c4 + 0) * 65 + r] = v.x;
      sT[(c4 + 1) * 65 + r] = v.y;
      sT[(c4 + 2) * 65 + r] = v.z;
      sT[(c4 + 3) * 65 + r] = v.w;
    }
    __syncthreads();
#pragma unroll
    for (int i = 0; i < 2; ++i) {
      const int idx = i * 256 + tid;
      const int rr = idx >> 3, ch = (idx & 7) * 8;
      us8 o;
#pragma unroll
      for (int jj = 0; jj < 8; ++jj) o[jj] = f2bf(sT[rr * 65 + ch + jj]);
      *(us8*)&dst[(size_t)(n0 + rr) * K + k0 + ch] = o;
    }
  } else if (bid < 1168) {  // zero d_out (2M floats)
    const int blk = bid - 912;
    const float4 z4 = {0.f, 0.f, 0.f, 0.f};
#pragma unroll
    for (int i = 0; i < 8; ++i)
      ((float4*)outZ)[(size_t)blk * 2048 + i * 256 + tid] = z4;
  } else if (bid < 1176) {  // zero lsum (32768 floats)
    const int blk = bid - 1168;
    const float4 z4 = {0.f, 0.f, 0.f, 0.f};
#pragma unroll
    for (int i = 0; i < 4; ++i)
      ((float4*)lsumZ)[(size_t)blk * 1024 + i * 256 + tid] = z4;
  } else {  // zero Qcomb qp-half of row 1023 (both streams)
    const int t2 = tid >> 7, rem = tid & 127;
    const int h = rem >> 4, d4 = (rem & 15) * 4;
    ushort4 z = make_ushort4(0, 0, 0, 0);
    *(ushort4*)&Qcomb[((size_t)t2 * ROWS + 1023) * 1024 + h * 128 + 64 + d4] = z;
  }
}

// ============================================================
// proj+pe MFMA GEMM. bx<32: D = f16emb[2048x512] @ WtAll[n][k];
// bx>=32: kp = gpe16[2048x128] @ WpT[n][k]. Tile 128(M)x64(N), BK=64.
// Epilogue via LDS transpose -> coalesced us8 stores into
// Qcomb ([qc|qp_shifted] per head), Kcomb ([kh|kp]), vhT ([d][k]).
// ============================================================
__global__ __launch_bounds__(256, 2) void projpe_kernel(
    const ushort_t* __restrict__ f16emb, const ushort_t* __restrict__ gpe16,
    const ushort_t* __restrict__ WtAll, const ushort_t* __restrict__ WpT,
    const float* __restrict__ Wu_b, const float* __restrict__ Wq_b,
    const float* __restrict__ Wkv_b, const float* __restrict__ Wp_b,
    const float* __restrict__ Buc, const float* __restrict__ Bup,
    const float* __restrict__ Bfc, const float* __restrict__ Bfp,
    ushort_t* __restrict__ Qcomb, ushort_t* __restrict__ Kcomb,
    ushort_t* __restrict__ vhT) {
  const int bx = blockIdx.x;
  const int mb = blockIdx.y * 128;
  const int tid = threadIdx.x;
  const int w = tid >> 6, lane = tid & 63;
  const int ln = lane & 15, quad = lane >> 4;
  const int wm = (w >> 1) * 64, wn = (w & 1) * 32;

  __shared__ __align__(16) ushort_t sA[128 * 72];
  __shared__ __align__(16) ushort_t sB[64 * 72];

  const bool isPe = (bx >= 32);
  const int nb = isPe ? 0 : bx * 64;
  const int npbase = isPe ? (bx - 32) * 64 : 0;
  const ushort_t* Ap = isPe ? gpe16 : f16emb;
  const int lda = isPe ? 128 : 512;
  const ushort_t* Bbase =
      isPe ? (WpT + (size_t)npbase * 128) : (WtAll + (size_t)nb * 512);
  const int ldb = isPe ? 128 : 512;
  const int trips = isPe ? 2 : 8;

  f32x4 acc[4][2];
#pragma unroll
  for (int rt = 0; rt < 4; ++rt)
#pragma unroll
    for (int ct = 0; ct < 2; ++ct) acc[rt][ct] = (f32x4){0.f, 0.f, 0.f, 0.f};

  uint4 pA[4], pB[2];
#pragma unroll
  for (int i = 0; i < 4; ++i) {
    const int idx = tid + i * 256;
    pA[i] = *(const uint4*)&Ap[(size_t)(mb + (idx >> 3)) * lda + (idx & 7) * 8];
  }
#pragma unroll
  for (int i = 0; i < 2; ++i) {
    const int idx = tid + i * 256;
    pB[i] = *(const uint4*)&Bbase[(size_t)(idx >> 3) * ldb + (idx & 7) * 8];
  }

  for (int t0 = 0; t0 < trips; ++t0) {
    __syncthreads();
#pragma unroll
    for (int i = 0; i < 4; ++i) {
      const int idx = tid + i * 256;
      *(uint4*)&sA[(idx >> 3) * 72 + (idx & 7) * 8] = pA[i];
    }
#pragma unroll
    for (int i = 0; i < 2; ++i) {
      const int idx = tid + i * 256;
      *(uint4*)&sB[(idx >> 3) * 72 + (idx & 7) * 8] = pB[i];
    }
    __syncthreads();
    if (t0 < trips - 1) {
      const int k1 = (t0 + 1) * 64;
#pragma unroll
      for (int i = 0; i < 4; ++i) {
        const int idx = tid + i * 256;
        pA[i] = *(const uint4*)&Ap[(size_t)(mb + (idx >> 3)) * lda + k1 +
                                   (idx & 7) * 8];
      }
#pragma unroll
      for (int i = 0; i < 2; ++i) {
        const int idx = tid + i * 256;
        pB[i] =
            *(const uint4*)&Bbase[(size_t)(idx >> 3) * ldb + k1 + (idx & 7) * 8];
      }
    }
#pragma unroll
    for (int kc = 0; kc < 2; ++kc) {
      bhalf8 af[4], bf_[2];
#pragma unroll
      for (int rt = 0; rt < 4; ++rt)
        af[rt] =
            *(const bhalf8*)&sA[(wm + rt * 16 + ln) * 72 + kc * 32 + quad * 8];
#pragma unroll
      for (int ct = 0; ct < 2; ++ct)
        bf_[ct] =
            *(const bhalf8*)&sB[(wn + ct * 16 + ln) * 72 + kc * 32 + quad * 8];
#pragma unroll
      for (int rt = 0; rt < 4; ++rt)
#pragma unroll
        for (int ct = 0; ct < 2; ++ct)
          acc[rt][ct] = __builtin_amdgcn_mfma_f32_16x16x32_bf16(
              af[rt], bf_[ct], acc[rt][ct], 0, 0, 0);
    }
  }

  // ---------- epilogue ----------
  __syncthreads();  // sA/sB reads done; reuse sA as sOut
  ushort_t* sOut = sA;

  if (!isPe && nb >= 1536) {
    // vh: dump TRANSPOSED sOut[n_loc][136-stride m]; store us8 along m
#pragma unroll
    for (int ct = 0; ct < 2; ++ct) {
      const int nl = wn + ct * 16 + ln;
      const float wb = Wkv_b[nb + nl - 1024];
#pragma unroll
      for (int rt = 0; rt < 4; ++rt)
#pragma unroll
        for (int r = 0; r < 4; ++r) {
          const int ml = wm + rt * 16 + quad * 4 + r;
          sOut[nl * 136 + ml] = f2bf(fast_tanh(acc[rt][ct][r] + wb));
        }
    }
    __syncthreads();
    const int b = mb >> 10, mo = mb & 1023;
#pragma unroll
    for (int i = 0; i < 4; ++i) {
      const int idx = tid + i * 256;
      const int nl = idx >> 4, m8 = (idx & 15) * 8;
      const us8 v = *(const us8*)&sOut[nl * 136 + m8];
      *(us8*)&vhT[((size_t)b * 512 + (nb - 1536) + nl) * 1024 + mo + m8] = v;
    }
  } else {
    // row-major dump sOut[m_loc][72]
    const float* WB = isPe ? Wp_b : (nb < 512 ? Wu_b : (nb < 1024 ? Wq_b : Wkv_b));
    const int woff = isPe ? npbase : (nb < 512 ? nb : (nb < 1024 ? nb - 512 : nb - 1024));
    const bool rawDump = (!isPe && nb < 1024);  // q: dump raw acc+wb; else tanh'd
#pragma unroll
    for (int ct = 0; ct < 2; ++ct) {
      const int nl = wn + ct * 16 + ln;
      const float wb = WB[woff + nl];
#pragma unroll
      for (int rt = 0; rt < 4; ++rt)
#pragma unroll
        for (int r = 0; r < 4; ++r) {
          const int ml = wm + rt * 16 + quad * 4 + r;
          const float v = acc[rt][ct][r] + wb;
          sOut[ml * 72 + nl] = f2bf(rawDump ? v : fast_tanh(v));
        }
    }
    __syncthreads();
#pragma unroll
    for (int i = 0; i < 4; ++i) {
      const int idx = tid + i * 256;
      const int rr = idx >> 3, c8 = (idx & 7) * 8;
      const int m = mb + rr;
      const us8 v = *(const us8*)&sOut[rr * 72 + c8];
      if (isPe) {
        const int n = npbase + c8;
        const int h = n >> 6;
        *(us8*)&Kcomb[(size_t)m * 1024 + h * 128 + 64 + (n & 63)] = v;
      } else if (nb < 1024) {
        const int strm = nb >= 512 ? 1 : 0;
        const int n = (nb - strm * 512) + c8;
        const int h = n >> 6;
        const float* BC = strm ? Bfc : Buc;
        const float* BP = strm ? Bfp : Bup;
        float bcA[8], bpA[8];
        *(float4*)&bcA[0] = *(const float4*)&BC[n];
        *(float4*)&bcA[4] = *(const float4*)&BC[n + 4];
        *(float4*)&bpA[0] = *(const float4*)&BP[n];
        *(float4*)&bpA[4] = *(const float4*)&BP[n + 4];
        us8 oc, op;
#pragma unroll
        for (int jj = 0; jj < 8; ++jj) {
          const float vv = bf2f((unsigned short)v[jj]);
          oc[jj] = f2bf(fast_tanh(vv + bcA[jj]));
          op[jj] = f2bf(fast_tanh(vv + bpA[jj]));
        }
        *(us8*)&Qcomb[((size_t)strm * ROWS + m) * 1024 + h * 128 + (n & 63)] = oc;
        // qp pre-shift: b=0 rows -> m-1 (drop m==0); b=1 rows -> m
        if (m != 0) {
          const int mp = (m < 1024) ? m - 1 : m;
          *(us8*)&Qcomb[((size_t)strm * ROWS + mp) * 1024 + h * 128 + 64 +
                        (n & 63)] = op;
        }
      } else {  // kh
        const int n = (nb - 1024) + c8;
        const int h = n >> 6;
        *(us8*)&Kcomb[(size_t)m * 1024 + h * 128 + (n & 63)] = v;
      }
    }
  }
}

// ============================================================
// attn: uniform-chunk flash MFMA. 4352 units = 32 combos x 136 tri-tiles.
// Blocks 0..255: 9 units; 256..511: 8 units. Static-max softmax makes
// units independent -> partial O/l accumulated via fp32 atomicAdd.
// ============================================================
__global__ __launch_bounds__(256, 2) void attn_kernel(
    const ushort_t* __restrict__ Qcomb, const ushort_t* __restrict__ Kcomb,
    const ushort_t* __restrict__ vhT, float* __restrict__ outNum,
    float* __restrict__ lsumArr) {
  const int bid = blockIdx.x, tid = threadIdx.x;
  const int w = tid >> 6, lane = tid & 63;
  const int ln = lane & 15, quad = lane >> 4;
  const int C = bid < 256 ? 9 : 8;
  int g = bid < 256 ? bid * 9 : 2304 + (bid - 256) * 8;

  __shared__ __align__(16) ushort_t sQ[64 * 136];
  __shared__ __align__(16) ushort_t sK[64 * 136];
  __shared__ __align__(16) ushort_t sV[64 * 72];
  __shared__ __align__(16) ushort_t sP[64 * 72];

  int c = g / 136;
  int u = g - c * 136;
  int jt = (int)((sqrtf(8.f * u + 1.f) - 1.f) * 0.5f);
  while ((jt + 1) * (jt + 2) / 2 <= u) ++jt;
  while (jt * (jt + 1) / 2 > u) --jt;
  int kt = u - jt * (jt + 1) / 2;
  int t = c >> 4, b = (c >> 3) & 1, h = c & 7;

  uint4 pk[4], pv[2];
#pragma unroll
  for (int i = 0; i < 4; ++i) {
    const int idx = tid + i * 256;
    pk[i] = *(const uint4*)&Kcomb[((size_t)b * SS + kt * 64 + (idx >> 4)) * 1024 +
                                  h * 128 + (idx & 15) * 8];
  }
#pragma unroll
  for (int i = 0; i < 2; ++i) {
    const int idx = tid + i * 256;
    pv[i] = *(const uint4*)&vhT[((size_t)b * 512 + h * 64 + (idx >> 3)) * 1024 +
                                kt * 64 + (idx & 7) * 8];
  }

  f32x4 oacc[4];
#pragma unroll
  for (int ct = 0; ct < 4; ++ct) oacc[ct] = (f32x4){0.f, 0.f, 0.f, 0.f};
  float lsum[4] = {0.f, 0.f, 0.f, 0.f};
  bool newRow = true;

  for (int it = 0; it < C; ++it) {
    __syncthreads();
    if (newRow) {
#pragma unroll
      for (int i = 0; i < 4; ++i) {
        const int idx = tid + i * 256;
        const int r = idx >> 4, cc = (idx & 15) * 8;
        *(uint4*)&sQ[r * 136 + cc] =
            *(const uint4*)&Qcomb[((size_t)t * ROWS + b * SS + jt * 64 + r) *
                                      1024 + h * 128 + cc];
      }
    }
#pragma unroll
    for (int i = 0; i < 4; ++i) {
      const int idx = tid + i * 256;
      *(uint4*)&sK[(idx >> 4) * 136 + (idx & 15) * 8] = pk[i];
    }
#pragma unroll
    for (int i = 0; i < 2; ++i) {
      const int idx = tid + i * 256;
      *(uint4*)&sV[(idx >> 3) * 72 + (idx & 7) * 8] = pv[i];
    }
    __syncthreads();

    // next-unit coords + prefetch
    int kt2 = kt + 1, jt2 = jt, c2 = c;
    if (kt2 > jt) {
      jt2 = jt + 1; kt2 = 0;
      if (jt2 > 15) { c2 = c + 1; jt2 = 0; }
    }
    if (it < C - 1) {
      const int b2 = (c2 >> 3) & 1, h2 = c2 & 7;
#pragma unroll
      for (int i = 0; i < 4; ++i) {
        const int idx = tid + i * 256;
        pk[i] = *(const uint4*)&Kcomb[((size_t)b2 * SS + kt2 * 64 + (idx >> 4)) *
                                          1024 + h2 * 128 + (idx & 15) * 8];
      }
#pragma unroll
      for (int i = 0; i < 2; ++i) {
        const int idx = tid + i * 256;
        pv[i] = *(const uint4*)&vhT[((size_t)b2 * 512 + h2 * 64 + (idx >> 3)) *
                                        1024 + kt2 * 64 + (idx & 7) * 8];
      }
    }

    bhalf8 aq[4];
#pragma unroll
    for (int kc = 0; kc < 4; ++kc)
      aq[kc] = *(const bhalf8*)&sQ[(w * 16 + ln) * 136 + kc * 32 + quad * 8];

    f32x4 sacc[4];
#pragma unroll
    for (int ct = 0; ct < 4; ++ct) {
      sacc[ct] = (f32x4){0.f, 0.f, 0.f, 0.f};
#pragma unroll
      for (int kc = 0; kc < 4; ++kc) {
        const bhalf8 bk =
            *(const bhalf8*)&sK[(ct * 16 + ln) * 136 + kc * 32 + quad * 8];
        sacc[ct] = __builtin_amdgcn_mfma_f32_16x16x32_bf16(aq[kc], bk,
                                                           sacc[ct], 0, 0, 0);
      }
    }

    const bool diag = (kt == jt);
#pragma unroll
    for (int ct = 0; ct < 4; ++ct)
#pragma unroll
      for (int r = 0; r < 4; ++r) {
        float p;
        if (diag && (ct * 16 + ln > w * 16 + quad * 4 + r))
          p = 0.f;
        else
          p = __expf(sacc[ct][r] * 0.125f - 16.f);
        sacc[ct][r] = p;
        lsum[r] += p;
      }

#pragma unroll
    for (int ct = 0; ct < 4; ++ct)
#pragma unroll
      for (int r = 0; r < 4; ++r)
        sP[(w * 16 + quad * 4 + r) * 72 + ct * 16 + ln] = f2bf(sacc[ct][r]);

#pragma unroll
    for (int kc = 0; kc < 2; ++kc) {
      const bhalf8 ap =
          *(const bhalf8*)&sP[(w * 16 + ln) * 72 + kc * 32 + quad * 8];
#pragma unroll
      for (int ct = 0; ct < 4; ++ct) {
        const bhalf8 bv =
            *(const bhalf8*)&sV[(ct * 16 + ln) * 72 + kc * 32 + quad * 8];
        oacc[ct] =
            __builtin_amdgcn_mfma_f32_16x16x32_bf16(ap, bv, oacc[ct], 0, 0, 0);
      }
    }

    newRow = (jt2 != jt) || (c2 != c);
    if (newRow || it == C - 1) {
      // flush partials for (t,b,h,jt)
#pragma unroll
      for (int r = 0; r < 4; ++r) {
        float s = lsum[r];
        s += __shfl_xor(s, 1);
        s += __shfl_xor(s, 2);
        s += __shfl_xor(s, 4);
        s += __shfl_xor(s, 8);
        const int j = jt * 64 + w * 16 + quad * 4 + r;
        if (ln == 0)
          atomicAdd(&lsumArr[((((t * 2 + b) << 10) + j) << 3) + h], s);
        const size_t orow = (((size_t)t * ROWS + b * SS + j) << 9) + h * 64;
#pragma unroll
        for (int ct = 0; ct < 4; ++ct)
          atomicAdd(&outNum[orow + ct * 16 + ln], oacc[ct][r]);
        lsum[r] = 0.f;
      }
#pragma unroll
      for (int ct = 0; ct < 4; ++ct) oacc[ct] = (f32x4){0.f, 0.f, 0.f, 0.f};
    }
    kt = kt2;
    jt = jt2;
    if (c2 != c) { c = c2; t = c >> 4; b = (c >> 3) & 1; h = c & 7; }
  }
}

// ============================================================
// ln: y = resid + num/l, layernorm, in-place on d_out
// ============================================================
__global__ __launch_bounds__(64) void ln_kernel(
    const float* __restrict__ u_emb, const float* __restrict__ f_emb,
    const float* __restrict__ lsumArr, float* __restrict__ out) {
  const int rid = blockIdx.x;
  const int t = rid >> 11, row = rid & 2047;
  const int b = row >> 10, j = row & 1023;
  const float* resid = t ? f_emb : u_emb;
  const int tid = threadIdx.x;
  const size_t base = (size_t)row * 512;
  const size_t obase = ((size_t)t * ROWS + row) * 512;
  const int o = tid * 8;
  const int h = tid >> 3;
  const float inv = 1.f / lsumArr[((((t * 2 + b) << 10) + j) << 3) + h];

  const float4 n0 = *(const float4*)&out[obase + o];
  const float4 n1 = *(const float4*)&out[obase + o + 4];
  const float4 r0 = *(const float4*)&resid[base + o];
  const float4 r1 = *(const float4*)&resid[base + o + 4];
  float4 y0, y1;
  y0.x = r0.x + n0.x * inv; y0.y = r0.y + n0.y * inv;
  y0.z = r0.z + n0.z * inv; y0.w = r0.w + n0.w * inv;
  y1.x = r1.x + n1.x * inv; y1.y = r1.y + n1.y * inv;
  y1.z = r1.z + n1.z * inv; y1.w = r1.w + n1.w * inv;

  float s = y0.x + y0.y + y0.z + y0.w + y1.x + y1.y + y1.z + y1.w;
  float q = y0.x * y0.x + y0.y * y0.y + y0.z * y0.z + y0.w * y0.w +
            y1.x * y1.x + y1.y * y1.y + y1.z * y1.z + y1.w * y1.w;
#pragma unroll
  for (int off = 1; off < 64; off <<= 1) {
    s += __shfl_xor(s, off);
    q += __shfl_xor(q, off);
  }
  const float mean = s * (1.f / 512.f);
  const float var = q * (1.f / 512.f) - mean * mean;
  const float rstd = rsqrtf(var + 1e-5f);

  float4 o0, o1;
  o0.x = (y0.x - mean) * rstd; o0.y = (y0.y - mean) * rstd;
  o0.z = (y0.z - mean) * rstd; o0.w = (y0.w - mean) * rstd;
  o1.x = (y1.x - mean) * rstd; o1.y = (y1.y - mean) * rstd;
  o1.z = (y1.z - mean) * rstd; o1.w = (y1.w - mean) * rstd;
  *(float4*)&out[obase + o] = o0;
  *(float4*)&out[obase + o + 4] = o1;
}

// ============================================================
extern "C" void kernel_launch(void* const* d_in, const int* in_sizes, int n_in,
                              void* d_out, int out_size, void* d_ws,
                              size_t ws_size, hipStream_t stream) {
  (void)in_sizes; (void)n_in; (void)out_size; (void)ws_size;
  const float* u_emb = (const float*)d_in[0];
  const float* f_emb = (const float*)d_in[1];
  const float* gpe = (const float*)d_in[2];
  const float* Wq_w = (const float*)d_in[5];
  const float* Wq_b = (const float*)d_in[6];
  const float* Wkv_w = (const float*)d_in[7];
  const float* Wkv_b = (const float*)d_in[8];
  const float* Wp_w = (const float*)d_in[9];
  const float* Wp_b = (const float*)d_in[10];
  const float* Wu_w = (const float*)d_in[11];
  const float* Wu_b = (const float*)d_in[12];
  const float* Bfc = (const float*)d_in[13];
  const float* Bfp = (const float*)d_in[14];
  const float* Buc = (const float*)d_in[15];
  const float* Bup = (const float*)d_in[16];
  float* out = (float*)d_out;

  ushort_t* ws = (ushort_t*)d_ws;
  const size_t SZ = (size_t)ROWS * EMB;  // 1048576
  ushort_t* Qcomb = ws;                  // 4*SZ (2 streams x 2048 x 1024)
  ushort_t* Kcomb = ws + 4 * SZ;         // 2*SZ (2048 x 1024)
  ushort_t* vhT = ws + 6 * SZ;           // 1*SZ (2x512 x 1024)
  float* lsumArr = (float*)(ws + 7 * SZ);        // 32768 floats
  ushort_t* ov = ws + 7 * SZ + 65536;
  ushort_t* f16emb = ov;                  // SZ
  ushort_t* gpe16 = ov + SZ;              // 262144
  ushort_t* WtAll = ov + SZ + 262144;     // SZ
  ushort_t* WpT = ov + 2 * SZ + 262144;   // 65536

  dim3 blk(256);
  hipLaunchKernelGGL(prep_kernel, dim3(1177), blk, 0, stream, f_emb, gpe, Wu_w,
                     Wq_w, Wkv_w, Wp_w, f16emb, gpe16, WtAll, WpT, out,
                     lsumArr, Qcomb);
  hipLaunchKernelGGL(projpe_kernel, dim3(40, 16), blk, 0, stream, f16emb,
                     gpe16, WtAll, WpT, Wu_b, Wq_b, Wkv_b, Wp_b, Buc, Bup, Bfc,
                     Bfp, Qcomb, Kcomb, vhT);
  hipLaunchKernelGGL(attn_kernel, dim3(512), blk, 0, stream, Qcomb, Kcomb, vhT,
                     out, lsumArr);
  hipLaunchKernelGGL(ln_kernel, dim3(4096), dim3(64), 0, stream, u_emb, f_emb,
                     lsumArr, out);
}

// Round 6
// 183.824 us; speedup vs baseline: 1.1028x; 1.1028x over previous
//
#include <hip/hip_runtime.h>
#include <math.h>

#define EMB 512
#define NH 8
#define HD 64
#define BB 2
#define SS 1024
#define ROWS (BB * SS) /* 2048 */

typedef __attribute__((ext_vector_type(8))) short bhalf8;
typedef __attribute__((ext_vector_type(4))) float f32x4;
typedef __attribute__((ext_vector_type(8))) unsigned short us8;
typedef unsigned short ushort_t;

__device__ __forceinline__ unsigned short f2bf(float x) {
  unsigned u = __float_as_uint(x);
  u = (u + 0x7FFFu + ((u >> 16) & 1u)) >> 16;
  return (unsigned short)u;
}
__device__ __forceinline__ float bf2f(unsigned short v) {
  return __uint_as_float(((unsigned)v) << 16);
}
__device__ __forceinline__ float fast_tanh(float x) {
  x = fminf(15.f, fmaxf(-15.f, x));
  const float e = __expf(2.f * x);
  return (e - 1.f) / (e + 1.f);
}

// ============================================================
// prep: weight transpose+convert (272 tiles) + zero qp row 1023 + ctr=256
// ============================================================
__global__ __launch_bounds__(256) void prep_kernel(
    const float* __restrict__ Wu, const float* __restrict__ Wq,
    const float* __restrict__ Wkv, const float* __restrict__ Wp,
    ushort_t* __restrict__ WtAll, ushort_t* __restrict__ WpT,
    ushort_t* __restrict__ Qcomb, int* __restrict__ ctr) {
  const int bid = blockIdx.x, tid = threadIdx.x;
  if (bid == 272) {
    if (tid == 0) ctr[0] = 256;
    const int t2 = tid >> 7, rem = tid & 127;
    const int h = rem >> 4, d4 = (rem & 15) * 4;
    ushort4 z = make_ushort4(0, 0, 0, 0);
    *(ushort4*)&Qcomb[((size_t)t2 * ROWS + 1023) * 1024 + h * 128 + 64 + d4] = z;
    return;
  }
  __shared__ float sT[64 * 65];
  int z = bid;
  const float* src;
  ushort_t* dst;
  int K, N, n0, k0;
  if (z < 64) {
    src = Wu; dst = WtAll; K = 512; N = 512;
    n0 = (z & 7) * 64; k0 = (z >> 3) * 64;
  } else if (z < 128) {
    z -= 64; src = Wq; dst = WtAll + 512 * 512; K = 512; N = 512;
    n0 = (z & 7) * 64; k0 = (z >> 3) * 64;
  } else if (z < 256) {
    z -= 128; src = Wkv; dst = WtAll + 1024 * 512; K = 512; N = 1024;
    n0 = (z & 15) * 64; k0 = (z >> 4) * 64;
  } else {
    z -= 256; src = Wp; dst = WpT; K = 128; N = 512;
    n0 = (z & 7) * 64; k0 = (z >> 3) * 64;
  }
#pragma unroll
  for (int i = 0; i < 4; ++i) {
    const int idx = i * 256 + tid;
    const int r = idx >> 4, c4 = (idx & 15) * 4;
    const float4 v = *(const float4*)&src[(size_t)(k0 + r) * N + n0 + c4];
    sT[(c4 + 0) * 65 + r] = v.x;
    sT[(c4 + 1) * 65 + r] = v.y;
    sT[(c4 + 2) * 65 + r] = v.z;
    sT[(c4 + 3) * 65 + r] = v.w;
  }
  __syncthreads();
#pragma unroll
  for (int i = 0; i < 2; ++i) {
    const int idx = i * 256 + tid;
    const int rr = idx >> 3, ch = (idx & 7) * 8;
    us8 o;
#pragma unroll
    for (int jj = 0; jj < 8; ++jj) o[jj] = f2bf(sT[rr * 65 + ch + jj]);
    *(us8*)&dst[(size_t)(n0 + rr) * K + k0 + ch] = o;
  }
}

// ============================================================
// proj+pe MFMA GEMM. A staged directly from fp32 (f_emb or gpe),
// converted to bf16 while writing LDS. bx<32: main (trips=8);
// bx>=32: pe (trips=2). Tile 128(M)x64(N), BK=64.
// Outputs: Qcomb [t][m][h*128: qc|qp_shifted], Kcomb [m][h*128: kh|kp],
// vhT [b][d][k]. Coalesced us8 stores via LDS transpose.
// ============================================================
__global__ __launch_bounds__(256, 2) void projpe_kernel(
    const float* __restrict__ f_emb, const float* __restrict__ gpe,
    const ushort_t* __restrict__ WtAll, const ushort_t* __restrict__ WpT,
    const float* __restrict__ Wu_b, const float* __restrict__ Wq_b,
    const float* __restrict__ Wkv_b, const float* __restrict__ Wp_b,
    const float* __restrict__ Buc, const float* __restrict__ Bup,
    const float* __restrict__ Bfc, const float* __restrict__ Bfp,
    ushort_t* __restrict__ Qcomb, ushort_t* __restrict__ Kcomb,
    ushort_t* __restrict__ vhT) {
  const int bx = blockIdx.x;
  const int mb = blockIdx.y * 128;
  const int tid = threadIdx.x;
  const int w = tid >> 6, lane = tid & 63;
  const int ln = lane & 15, quad = lane >> 4;
  const int wm = (w >> 1) * 64, wn = (w & 1) * 32;

  __shared__ __align__(16) ushort_t sA[128 * 72];
  __shared__ __align__(16) ushort_t sB[64 * 72];

  const bool isPe = (bx >= 32);
  const int nb = isPe ? 0 : bx * 64;
  const int npbase = isPe ? (bx - 32) * 64 : 0;
  const float* Af = isPe ? gpe : f_emb;
  const int lda = isPe ? 128 : 512;
  const ushort_t* Bbase =
      isPe ? (WpT + (size_t)npbase * 128) : (WtAll + (size_t)nb * 512);
  const int ldb = isPe ? 128 : 512;
  const int trips = isPe ? 2 : 8;

  f32x4 acc[4][2];
#pragma unroll
  for (int rt = 0; rt < 4; ++rt)
#pragma unroll
    for (int ct = 0; ct < 2; ++ct) acc[rt][ct] = (f32x4){0.f, 0.f, 0.f, 0.f};

  float4 qa[8];
  uint4 qb[2];
#pragma unroll
  for (int i = 0; i < 4; ++i) {
    const int idx = tid + i * 256;
    const size_t base = (size_t)(mb + (idx >> 3)) * lda + (idx & 7) * 8;
    qa[2 * i] = *(const float4*)&Af[base];
    qa[2 * i + 1] = *(const float4*)&Af[base + 4];
  }
#pragma unroll
  for (int i = 0; i < 2; ++i) {
    const int idx = tid + i * 256;
    qb[i] = *(const uint4*)&Bbase[(size_t)(idx >> 3) * ldb + (idx & 7) * 8];
  }

  for (int t0 = 0; t0 < trips; ++t0) {
    __syncthreads();
#pragma unroll
    for (int i = 0; i < 4; ++i) {
      const int idx = tid + i * 256;
      us8 o;
      const float4 a = qa[2 * i], b = qa[2 * i + 1];
      o[0] = f2bf(a.x); o[1] = f2bf(a.y); o[2] = f2bf(a.z); o[3] = f2bf(a.w);
      o[4] = f2bf(b.x); o[5] = f2bf(b.y); o[6] = f2bf(b.z); o[7] = f2bf(b.w);
      *(us8*)&sA[(idx >> 3) * 72 + (idx & 7) * 8] = o;
    }
#pragma unroll
    for (int i = 0; i < 2; ++i) {
      const int idx = tid + i * 256;
      *(uint4*)&sB[(idx >> 3) * 72 + (idx & 7) * 8] = qb[i];
    }
    __syncthreads();
    if (t0 < trips - 1) {
      const int k1 = (t0 + 1) * 64;
#pragma unroll
      for (int i = 0; i < 4; ++i) {
        const int idx = tid + i * 256;
        const size_t base = (size_t)(mb + (idx >> 3)) * lda + k1 + (idx & 7) * 8;
        qa[2 * i] = *(const float4*)&Af[base];
        qa[2 * i + 1] = *(const float4*)&Af[base + 4];
      }
#pragma unroll
      for (int i = 0; i < 2; ++i) {
        const int idx = tid + i * 256;
        qb[i] =
            *(const uint4*)&Bbase[(size_t)(idx >> 3) * ldb + k1 + (idx & 7) * 8];
      }
    }
#pragma unroll
    for (int kc = 0; kc < 2; ++kc) {
      bhalf8 af[4], bf_[2];
#pragma unroll
      for (int rt = 0; rt < 4; ++rt)
        af[rt] =
            *(const bhalf8*)&sA[(wm + rt * 16 + ln) * 72 + kc * 32 + quad * 8];
#pragma unroll
      for (int ct = 0; ct < 2; ++ct)
        bf_[ct] =
            *(const bhalf8*)&sB[(wn + ct * 16 + ln) * 72 + kc * 32 + quad * 8];
#pragma unroll
      for (int rt = 0; rt < 4; ++rt)
#pragma unroll
        for (int ct = 0; ct < 2; ++ct)
          acc[rt][ct] = __builtin_amdgcn_mfma_f32_16x16x32_bf16(
              af[rt], bf_[ct], acc[rt][ct], 0, 0, 0);
    }
  }

  // ---------- epilogue ----------
  __syncthreads();
  ushort_t* sOut = sA;

  if (!isPe && nb >= 1536) {
    // vh -> transposed vhT[d][k]
#pragma unroll
    for (int ct = 0; ct < 2; ++ct) {
      const int nl = wn + ct * 16 + ln;
      const float wb = Wkv_b[nb + nl - 1024];
#pragma unroll
      for (int rt = 0; rt < 4; ++rt)
#pragma unroll
        for (int r = 0; r < 4; ++r) {
          const int ml = wm + rt * 16 + quad * 4 + r;
          sOut[nl * 136 + ml] = f2bf(fast_tanh(acc[rt][ct][r] + wb));
        }
    }
    __syncthreads();
    const int b = mb >> 10, mo = mb & 1023;
#pragma unroll
    for (int i = 0; i < 4; ++i) {
      const int idx = tid + i * 256;
      const int nl = idx >> 4, m8 = (idx & 15) * 8;
      const us8 v = *(const us8*)&sOut[nl * 136 + m8];
      *(us8*)&vhT[((size_t)b * 512 + (nb - 1536) + nl) * 1024 + mo + m8] = v;
    }
  } else {
    const float* WB =
        isPe ? Wp_b : (nb < 512 ? Wu_b : (nb < 1024 ? Wq_b : Wkv_b));
    const int woff =
        isPe ? npbase : (nb < 512 ? nb : (nb < 1024 ? nb - 512 : nb - 1024));
    const bool rawDump = (!isPe && nb < 1024);
#pragma unroll
    for (int ct = 0; ct < 2; ++ct) {
      const int nl = wn + ct * 16 + ln;
      const float wb = WB[woff + nl];
#pragma unroll
      for (int rt = 0; rt < 4; ++rt)
#pragma unroll
        for (int r = 0; r < 4; ++r) {
          const int ml = wm + rt * 16 + quad * 4 + r;
          const float v = acc[rt][ct][r] + wb;
          sOut[ml * 72 + nl] = f2bf(rawDump ? v : fast_tanh(v));
        }
    }
    __syncthreads();
#pragma unroll
    for (int i = 0; i < 4; ++i) {
      const int idx = tid + i * 256;
      const int rr = idx >> 3, c8 = (idx & 7) * 8;
      const int m = mb + rr;
      const us8 v = *(const us8*)&sOut[rr * 72 + c8];
      if (isPe) {
        const int n = npbase + c8;
        const int h = n >> 6;
        *(us8*)&Kcomb[(size_t)m * 1024 + h * 128 + 64 + (n & 63)] = v;
      } else if (nb < 1024) {
        const int strm = nb >= 512 ? 1 : 0;
        const int n = (nb - strm * 512) + c8;
        const int h = n >> 6;
        const float* BC = strm ? Bfc : Buc;
        const float* BP = strm ? Bfp : Bup;
        float bcA[8], bpA[8];
        *(float4*)&bcA[0] = *(const float4*)&BC[n];
        *(float4*)&bcA[4] = *(const float4*)&BC[n + 4];
        *(float4*)&bpA[0] = *(const float4*)&BP[n];
        *(float4*)&bpA[4] = *(const float4*)&BP[n + 4];
        us8 oc, op;
#pragma unroll
        for (int jj = 0; jj < 8; ++jj) {
          const float vv = bf2f((unsigned short)v[jj]);
          oc[jj] = f2bf(fast_tanh(vv + bcA[jj]));
          op[jj] = f2bf(fast_tanh(vv + bpA[jj]));
        }
        *(us8*)&Qcomb[((size_t)strm * ROWS + m) * 1024 + h * 128 + (n & 63)] =
            oc;
        if (m != 0) {
          const int mp = (m < 1024) ? m - 1 : m;
          *(us8*)&Qcomb[((size_t)strm * ROWS + mp) * 1024 + h * 128 + 64 +
                        (n & 63)] = op;
        }
      } else {  // kh
        const int n = (nb - 1024) + c8;
        const int h = n >> 6;
        *(us8*)&Kcomb[(size_t)m * 1024 + h * 128 + (n & 63)] = v;
      }
    }
  }
}

// ============================================================
// attn: work-stealing flash MFMA. 512 units = (t,b,h,jt), ordered
// heavy-first (jt = 15 - u/32). Grid 256 (1 block/CU); blocks grab
// units via atomicAdd -> LPT balance. Output: normalized bf16 attO.
// ============================================================
__global__ __launch_bounds__(256, 1) void attn_kernel(
    const ushort_t* __restrict__ Qcomb, const ushort_t* __restrict__ Kcomb,
    const ushort_t* __restrict__ vhT, ushort_t* __restrict__ attO,
    int* __restrict__ ctr) {
  const int tid = threadIdx.x;
  const int w = tid >> 6, lane = tid & 63;
  const int ln = lane & 15, quad = lane >> 4;

  __shared__ __align__(16) ushort_t sQ[64 * 136];
  __shared__ __align__(16) ushort_t sK[64 * 136];
  __shared__ __align__(16) ushort_t sV[64 * 72];
  __shared__ __align__(16) ushort_t sP[64 * 72];
  __shared__ int sg;

  int u = blockIdx.x;
  while (u < 512) {
    const int jt = 15 - (u >> 5);
    const int c = u & 31, t = c >> 4, b = (c >> 3) & 1, h = c & 7;

    // stage Q + prefetch kt=0 K/V
    uint4 qq[4], pk[4], pv[2];
#pragma unroll
    for (int i = 0; i < 4; ++i) {
      const int idx = tid + i * 256;
      qq[i] = *(const uint4*)&Qcomb[((size_t)t * ROWS + b * SS + jt * 64 +
                                     (idx >> 4)) * 1024 + h * 128 +
                                    (idx & 15) * 8];
      pk[i] = *(const uint4*)&Kcomb[((size_t)b * SS + (idx >> 4)) * 1024 +
                                    h * 128 + (idx & 15) * 8];
    }
#pragma unroll
    for (int i = 0; i < 2; ++i) {
      const int idx = tid + i * 256;
      pv[i] = *(const uint4*)&vhT[((size_t)b * 512 + h * 64 + (idx >> 3)) *
                                      1024 + (idx & 7) * 8];
    }
#pragma unroll
    for (int i = 0; i < 4; ++i) {
      const int idx = tid + i * 256;
      *(uint4*)&sQ[(idx >> 4) * 136 + (idx & 15) * 8] = qq[i];
    }
    __syncthreads();

    bhalf8 aq[4];
#pragma unroll
    for (int kc = 0; kc < 4; ++kc)
      aq[kc] = *(const bhalf8*)&sQ[(w * 16 + ln) * 136 + kc * 32 + quad * 8];

    f32x4 oacc[4];
#pragma unroll
    for (int ct = 0; ct < 4; ++ct) oacc[ct] = (f32x4){0.f, 0.f, 0.f, 0.f};
    float lsum[4] = {0.f, 0.f, 0.f, 0.f};

    for (int kt = 0; kt <= jt; ++kt) {
      if (kt > 0) __syncthreads();
#pragma unroll
      for (int i = 0; i < 4; ++i) {
        const int idx = tid + i * 256;
        *(uint4*)&sK[(idx >> 4) * 136 + (idx & 15) * 8] = pk[i];
      }
#pragma unroll
      for (int i = 0; i < 2; ++i) {
        const int idx = tid + i * 256;
        *(uint4*)&sV[(idx >> 3) * 72 + (idx & 7) * 8] = pv[i];
      }
      __syncthreads();
      if (kt < jt) {
        const int k1 = (kt + 1) * 64;
#pragma unroll
        for (int i = 0; i < 4; ++i) {
          const int idx = tid + i * 256;
          pk[i] = *(const uint4*)&Kcomb[((size_t)b * SS + k1 + (idx >> 4)) *
                                            1024 + h * 128 + (idx & 15) * 8];
        }
#pragma unroll
        for (int i = 0; i < 2; ++i) {
          const int idx = tid + i * 256;
          pv[i] = *(const uint4*)&vhT[((size_t)b * 512 + h * 64 + (idx >> 3)) *
                                          1024 + k1 + (idx & 7) * 8];
        }
      }

      f32x4 sacc[4];
#pragma unroll
      for (int ct = 0; ct < 4; ++ct) {
        sacc[ct] = (f32x4){0.f, 0.f, 0.f, 0.f};
#pragma unroll
        for (int kc = 0; kc < 4; ++kc) {
          const bhalf8 bk =
              *(const bhalf8*)&sK[(ct * 16 + ln) * 136 + kc * 32 + quad * 8];
          sacc[ct] = __builtin_amdgcn_mfma_f32_16x16x32_bf16(aq[kc], bk,
                                                             sacc[ct], 0, 0, 0);
        }
      }

      const bool diag = (kt == jt);
#pragma unroll
      for (int ct = 0; ct < 4; ++ct)
#pragma unroll
        for (int r = 0; r < 4; ++r) {
          float p;
          if (diag && (ct * 16 + ln > w * 16 + quad * 4 + r))
            p = 0.f;
          else
            p = __expf(sacc[ct][r] * 0.125f - 16.f);
          sacc[ct][r] = p;
          lsum[r] += p;
        }

#pragma unroll
      for (int ct = 0; ct < 4; ++ct)
#pragma unroll
        for (int r = 0; r < 4; ++r)
          sP[(w * 16 + quad * 4 + r) * 72 + ct * 16 + ln] = f2bf(sacc[ct][r]);

#pragma unroll
      for (int kc = 0; kc < 2; ++kc) {
        const bhalf8 ap =
            *(const bhalf8*)&sP[(w * 16 + ln) * 72 + kc * 32 + quad * 8];
#pragma unroll
        for (int ct = 0; ct < 4; ++ct) {
          const bhalf8 bv =
              *(const bhalf8*)&sV[(ct * 16 + ln) * 72 + kc * 32 + quad * 8];
          oacc[ct] = __builtin_amdgcn_mfma_f32_16x16x32_bf16(ap, bv, oacc[ct],
                                                             0, 0, 0);
        }
      }
    }

    // epilogue: normalize, store bf16
#pragma unroll
    for (int r = 0; r < 4; ++r) {
      float s = lsum[r];
      s += __shfl_xor(s, 1);
      s += __shfl_xor(s, 2);
      s += __shfl_xor(s, 4);
      s += __shfl_xor(s, 8);
      const float inv = 1.f / s;
      const int j = jt * 64 + w * 16 + quad * 4 + r;
      const size_t orow = ((size_t)t * ROWS + b * SS + j) * 512 + h * 64;
#pragma unroll
      for (int ct = 0; ct < 4; ++ct)
        attO[orow + ct * 16 + ln] = f2bf(oacc[ct][r] * inv);
    }

    if (tid == 0) sg = atomicAdd(ctr, 1);
    __syncthreads();
    u = sg;
  }
}

// ============================================================
// ln: y = resid + attO(bf16, normalized), layernorm
// ============================================================
__global__ __launch_bounds__(64) void ln_kernel(
    const float* __restrict__ u_emb, const float* __restrict__ f_emb,
    const ushort_t* __restrict__ attO, float* __restrict__ out) {
  const int rid = blockIdx.x;
  const int t = rid >> 11, row = rid & 2047;
  const float* resid = t ? f_emb : u_emb;
  const int tid = threadIdx.x;
  const size_t base = (size_t)row * 512;
  const size_t obase = ((size_t)t * ROWS + row) * 512;
  const int o = tid * 8;

  const us8 a = *(const us8*)&attO[obase + o];
  const float4 r0 = *(const float4*)&resid[base + o];
  const float4 r1 = *(const float4*)&resid[base + o + 4];
  float y[8];
  y[0] = r0.x + bf2f((unsigned short)a[0]);
  y[1] = r0.y + bf2f((unsigned short)a[1]);
  y[2] = r0.z + bf2f((unsigned short)a[2]);
  y[3] = r0.w + bf2f((unsigned short)a[3]);
  y[4] = r1.x + bf2f((unsigned short)a[4]);
  y[5] = r1.y + bf2f((unsigned short)a[5]);
  y[6] = r1.z + bf2f((unsigned short)a[6]);
  y[7] = r1.w + bf2f((unsigned short)a[7]);

  float s = 0.f, q = 0.f;
#pragma unroll
  for (int i = 0; i < 8; ++i) {
    s += y[i];
    q += y[i] * y[i];
  }
#pragma unroll
  for (int off = 1; off < 64; off <<= 1) {
    s += __shfl_xor(s, off);
    q += __shfl_xor(q, off);
  }
  const float mean = s * (1.f / 512.f);
  const float var = q * (1.f / 512.f) - mean * mean;
  const float rstd = rsqrtf(var + 1e-5f);

  float4 o0, o1;
  o0.x = (y[0] - mean) * rstd; o0.y = (y[1] - mean) * rstd;
  o0.z = (y[2] - mean) * rstd; o0.w = (y[3] - mean) * rstd;
  o1.x = (y[4] - mean) * rstd; o1.y = (y[5] - mean) * rstd;
  o1.z = (y[6] - mean) * rstd; o1.w = (y[7] - mean) * rstd;
  *(float4*)&out[obase + o] = o0;
  *(float4*)&out[obase + o + 4] = o1;
}

// ============================================================
extern "C" void kernel_launch(void* const* d_in, const int* in_sizes, int n_in,
                              void* d_out, int out_size, void* d_ws,
                              size_t ws_size, hipStream_t stream) {
  (void)in_sizes; (void)n_in; (void)out_size; (void)ws_size;
  const float* u_emb = (const float*)d_in[0];
  const float* f_emb = (const float*)d_in[1];
  const float* gpe = (const float*)d_in[2];
  const float* Wq_w = (const float*)d_in[5];
  const float* Wq_b = (const float*)d_in[6];
  const float* Wkv_w = (const float*)d_in[7];
  const float* Wkv_b = (const float*)d_in[8];
  const float* Wp_w = (const float*)d_in[9];
  const float* Wp_b = (const float*)d_in[10];
  const float* Wu_w = (const float*)d_in[11];
  const float* Wu_b = (const float*)d_in[12];
  const float* Bfc = (const float*)d_in[13];
  const float* Bfp = (const float*)d_in[14];
  const float* Buc = (const float*)d_in[15];
  const float* Bup = (const float*)d_in[16];
  float* out = (float*)d_out;

  ushort_t* ws = (ushort_t*)d_ws;
  const size_t SZ = (size_t)ROWS * EMB;  // 1048576
  ushort_t* Qcomb = ws;                  // 4*SZ
  ushort_t* Kcomb = ws + 4 * SZ;         // 2*SZ
  ushort_t* vhT = ws + 6 * SZ;           // SZ
  ushort_t* attO = ws + 7 * SZ;          // 2*SZ (bf16, normalized)
  ushort_t* WtAll = ws + 9 * SZ;         // SZ
  ushort_t* WpT = ws + 10 * SZ;          // 65536
  int* ctr = (int*)(ws + 10 * SZ + 65536);

  dim3 blk(256);
  hipLaunchKernelGGL(prep_kernel, dim3(273), blk, 0, stream, Wu_w, Wq_w, Wkv_w,
                     Wp_w, WtAll, WpT, Qcomb, ctr);
  hipLaunchKernelGGL(projpe_kernel, dim3(40, 16), blk, 0, stream, f_emb, gpe,
                     WtAll, WpT, Wu_b, Wq_b, Wkv_b, Wp_b, Buc, Bup, Bfc, Bfp,
                     Qcomb, Kcomb, vhT);
  hipLaunchKernelGGL(attn_kernel, dim3(256), blk, 0, stream, Qcomb, Kcomb, vhT,
                     attO, ctr);
  hipLaunchKernelGGL(ln_kernel, dim3(4096), dim3(64), 0, stream, u_emb, f_emb,
                     attO, out);
}

// Round 7
// 170.798 us; speedup vs baseline: 1.1870x; 1.0763x over previous
//
#include <hip/hip_runtime.h>
#include <math.h>

#define EMB 512
#define NH 8
#define HD 64
#define BB 2
#define SS 1024
#define ROWS (BB * SS) /* 2048 */

typedef __attribute__((ext_vector_type(8))) short bhalf8;
typedef __attribute__((ext_vector_type(4))) float f32x4;
typedef __attribute__((ext_vector_type(8))) unsigned short us8;
typedef unsigned short ushort_t;

__device__ __forceinline__ unsigned short f2bf(float x) {
  unsigned u = __float_as_uint(x);
  u = (u + 0x7FFFu + ((u >> 16) & 1u)) >> 16;
  return (unsigned short)u;
}
__device__ __forceinline__ float bf2f(unsigned short v) {
  return __uint_as_float(((unsigned)v) << 16);
}
__device__ __forceinline__ float fast_tanh(float x) {
  x = fminf(15.f, fmaxf(-15.f, x));
  const float e = __expf(2.f * x);
  return (e - 1.f) / (e + 1.f);
}

// ============================================================
// proj+pe MFMA GEMM, prep-free. bx<32: main (f_emb @ [Wu|Wq|Wkv]),
// trips=8. bx>=32: pe (gpe @ Wp), trips=2. Tile 128(M)x64(N), BK=64.
// A staged fp32->bf16 direct from d_in. B transposed during staging
// from raw W[k][n]: thread (n=tid&63, kc=tid>>6) reads 16 scalars
// down column n, packs 2x us8 rows into sB[n][k] (2-way conflicts = free).
// Outputs: Qcomb [t][m][h*128: qc|qp_shifted], Kcomb [m][h*128: kh|kp],
// vhT [b][d][k]. Block(0,0) also zeroes Qcomb qp row 1023 (no writer).
// ============================================================
__global__ __launch_bounds__(256, 3) void projpe_kernel(
    const float* __restrict__ f_emb, const float* __restrict__ gpe,
    const float* __restrict__ Wu, const float* __restrict__ Wq,
    const float* __restrict__ Wkv, const float* __restrict__ Wp,
    const float* __restrict__ Wu_b, const float* __restrict__ Wq_b,
    const float* __restrict__ Wkv_b, const float* __restrict__ Wp_b,
    const float* __restrict__ Buc, const float* __restrict__ Bup,
    const float* __restrict__ Bfc, const float* __restrict__ Bfp,
    ushort_t* __restrict__ Qcomb, ushort_t* __restrict__ Kcomb,
    ushort_t* __restrict__ vhT) {
  const int bx = blockIdx.x;
  const int mb = blockIdx.y * 128;
  const int tid = threadIdx.x;
  const int w = tid >> 6, lane = tid & 63;
  const int ln = lane & 15, quad = lane >> 4;
  const int wm = (w >> 1) * 64, wn = (w & 1) * 32;

  __shared__ __align__(16) ushort_t sA[128 * 72];
  __shared__ __align__(16) ushort_t sB[64 * 72];

  if (bx == 0 && blockIdx.y == 0) {
    // zero Qcomb qp-half of row 1023, both streams (no other writer)
    const int t2 = tid >> 7, rem = tid & 127;
    const int h = rem >> 4, d4 = (rem & 15) * 4;
    *(ushort4*)&Qcomb[((size_t)t2 * ROWS + 1023) * 1024 + h * 128 + 64 + d4] =
        make_ushort4(0, 0, 0, 0);
  }

  const bool isPe = (bx >= 32);
  const int nb = isPe ? 0 : bx * 64;        // global col (main)
  const int npbase = isPe ? (bx - 32) * 64 : 0;  // pe col
  const float* Af = isPe ? gpe : f_emb;
  const int lda = isPe ? 128 : 512;
  const int trips = isPe ? 2 : 8;

  // B source: raw weight [K][Nw], column offset coff
  const float* Wsrc;
  int Nw, coff;
  if (isPe) { Wsrc = Wp; Nw = 512; coff = npbase; }
  else if (nb < 512) { Wsrc = Wu; Nw = 512; coff = nb; }
  else if (nb < 1024) { Wsrc = Wq; Nw = 512; coff = nb - 512; }
  else { Wsrc = Wkv; Nw = 1024; coff = nb - 1024; }

  const int bn = tid & 63;          // n within tile
  const int bk0 = (tid >> 6) * 16;  // k-chunk base (0,16,32,48)

  f32x4 acc[4][2];
#pragma unroll
  for (int rt = 0; rt < 4; ++rt)
#pragma unroll
    for (int ct = 0; ct < 2; ++ct) acc[rt][ct] = (f32x4){0.f, 0.f, 0.f, 0.f};

  float4 qa[8];
  float qbw[16];
#pragma unroll
  for (int i = 0; i < 4; ++i) {
    const int idx = tid + i * 256;
    const size_t base = (size_t)(mb + (idx >> 3)) * lda + (idx & 7) * 8;
    qa[2 * i] = *(const float4*)&Af[base];
    qa[2 * i + 1] = *(const float4*)&Af[base + 4];
  }
#pragma unroll
  for (int j = 0; j < 16; ++j)
    qbw[j] = Wsrc[(size_t)(bk0 + j) * Nw + coff + bn];

  for (int t0 = 0; t0 < trips; ++t0) {
    __syncthreads();
#pragma unroll
    for (int i = 0; i < 4; ++i) {
      const int idx = tid + i * 256;
      us8 o;
      const float4 a = qa[2 * i], b = qa[2 * i + 1];
      o[0] = f2bf(a.x); o[1] = f2bf(a.y); o[2] = f2bf(a.z); o[3] = f2bf(a.w);
      o[4] = f2bf(b.x); o[5] = f2bf(b.y); o[6] = f2bf(b.z); o[7] = f2bf(b.w);
      *(us8*)&sA[(idx >> 3) * 72 + (idx & 7) * 8] = o;
    }
    {
      us8 o0, o1;
#pragma unroll
      for (int j = 0; j < 8; ++j) {
        o0[j] = f2bf(qbw[j]);
        o1[j] = f2bf(qbw[8 + j]);
      }
      *(us8*)&sB[bn * 72 + bk0] = o0;
      *(us8*)&sB[bn * 72 + bk0 + 8] = o1;
    }
    __syncthreads();
    if (t0 < trips - 1) {
      const int k1 = (t0 + 1) * 64;
#pragma unroll
      for (int i = 0; i < 4; ++i) {
        const int idx = tid + i * 256;
        const size_t base = (size_t)(mb + (idx >> 3)) * lda + k1 + (idx & 7) * 8;
        qa[2 * i] = *(const float4*)&Af[base];
        qa[2 * i + 1] = *(const float4*)&Af[base + 4];
      }
#pragma unroll
      for (int j = 0; j < 16; ++j)
        qbw[j] = Wsrc[(size_t)(k1 + bk0 + j) * Nw + coff + bn];
    }
#pragma unroll
    for (int kc = 0; kc < 2; ++kc) {
      bhalf8 af[4], bf_[2];
#pragma unroll
      for (int rt = 0; rt < 4; ++rt)
        af[rt] =
            *(const bhalf8*)&sA[(wm + rt * 16 + ln) * 72 + kc * 32 + quad * 8];
#pragma unroll
      for (int ct = 0; ct < 2; ++ct)
        bf_[ct] =
            *(const bhalf8*)&sB[(wn + ct * 16 + ln) * 72 + kc * 32 + quad * 8];
#pragma unroll
      for (int rt = 0; rt < 4; ++rt)
#pragma unroll
        for (int ct = 0; ct < 2; ++ct)
          acc[rt][ct] = __builtin_amdgcn_mfma_f32_16x16x32_bf16(
              af[rt], bf_[ct], acc[rt][ct], 0, 0, 0);
    }
  }

  // ---------- epilogue ----------
  __syncthreads();
  ushort_t* sOut = sA;

  if (!isPe && nb >= 1536) {
    // vh -> transposed vhT[b][d][k]
#pragma unroll
    for (int ct = 0; ct < 2; ++ct) {
      const int nl = wn + ct * 16 + ln;
      const float wb = Wkv_b[nb + nl - 1024];
#pragma unroll
      for (int rt = 0; rt < 4; ++rt)
#pragma unroll
        for (int r = 0; r < 4; ++r) {
          const int ml = wm + rt * 16 + quad * 4 + r;
          sOut[nl * 136 + ml] = f2bf(fast_tanh(acc[rt][ct][r] + wb));
        }
    }
    __syncthreads();
    const int b = mb >> 10, mo = mb & 1023;
#pragma unroll
    for (int i = 0; i < 4; ++i) {
      const int idx = tid + i * 256;
      const int nl = idx >> 4, m8 = (idx & 15) * 8;
      const us8 v = *(const us8*)&sOut[nl * 136 + m8];
      *(us8*)&vhT[((size_t)b * 512 + (nb - 1536) + nl) * 1024 + mo + m8] = v;
    }
  } else {
    const float* WB =
        isPe ? Wp_b : (nb < 512 ? Wu_b : (nb < 1024 ? Wq_b : Wkv_b));
    const int woff =
        isPe ? npbase : (nb < 512 ? nb : (nb < 1024 ? nb - 512 : nb - 1024));
    const bool rawDump = (!isPe && nb < 1024);
#pragma unroll
    for (int ct = 0; ct < 2; ++ct) {
      const int nl = wn + ct * 16 + ln;
      const float wb = WB[woff + nl];
#pragma unroll
      for (int rt = 0; rt < 4; ++rt)
#pragma unroll
        for (int r = 0; r < 4; ++r) {
          const int ml = wm + rt * 16 + quad * 4 + r;
          const float v = acc[rt][ct][r] + wb;
          sOut[ml * 72 + nl] = f2bf(rawDump ? v : fast_tanh(v));
        }
    }
    __syncthreads();
#pragma unroll
    for (int i = 0; i < 4; ++i) {
      const int idx = tid + i * 256;
      const int rr = idx >> 3, c8 = (idx & 7) * 8;
      const int m = mb + rr;
      const us8 v = *(const us8*)&sOut[rr * 72 + c8];
      if (isPe) {
        const int n = npbase + c8;
        const int h = n >> 6;
        *(us8*)&Kcomb[(size_t)m * 1024 + h * 128 + 64 + (n & 63)] = v;
      } else if (nb < 1024) {
        const int strm = nb >= 512 ? 1 : 0;
        const int n = (nb - strm * 512) + c8;
        const int h = n >> 6;
        const float* BC = strm ? Bfc : Buc;
        const float* BP = strm ? Bfp : Bup;
        float bcA[8], bpA[8];
        *(float4*)&bcA[0] = *(const float4*)&BC[n];
        *(float4*)&bcA[4] = *(const float4*)&BC[n + 4];
        *(float4*)&bpA[0] = *(const float4*)&BP[n];
        *(float4*)&bpA[4] = *(const float4*)&BP[n + 4];
        us8 oc, op;
#pragma unroll
        for (int jj = 0; jj < 8; ++jj) {
          const float vv = bf2f((unsigned short)v[jj]);
          oc[jj] = f2bf(fast_tanh(vv + bcA[jj]));
          op[jj] = f2bf(fast_tanh(vv + bpA[jj]));
        }
        *(us8*)&Qcomb[((size_t)strm * ROWS + m) * 1024 + h * 128 + (n & 63)] =
            oc;
        if (m != 0) {
          const int mp = (m < 1024) ? m - 1 : m;
          *(us8*)&Qcomb[((size_t)strm * ROWS + mp) * 1024 + h * 128 + 64 +
                        (n & 63)] = op;
        }
      } else {  // kh
        const int n = (nb - 1024) + c8;
        const int h = n >> 6;
        *(us8*)&Kcomb[(size_t)m * 1024 + h * 128 + (n & 63)] = v;
      }
    }
  }
}

// ============================================================
// attn: flash MFMA, static-max softmax. 512 blocks = 512 units
// (t,b,h,jt); 2 blocks/CU for barrier/latency overlap. Unit order:
// bid<256 -> jt=15-(bid>>5) (heavy), bid>=256 -> jt=(bid-256)>>5
// (light), so bid and bid+256 sum to 15 if dispatch pairs them.
// ============================================================
__global__ __launch_bounds__(256, 2) void attn_kernel(
    const ushort_t* __restrict__ Qcomb, const ushort_t* __restrict__ Kcomb,
    const ushort_t* __restrict__ vhT, ushort_t* __restrict__ attO) {
  const int bid = blockIdx.x;
  const int tid = threadIdx.x;
  const int w = tid >> 6, lane = tid & 63;
  const int ln = lane & 15, quad = lane >> 4;

  __shared__ __align__(16) ushort_t sQ[64 * 136];
  __shared__ __align__(16) ushort_t sK[64 * 136];
  __shared__ __align__(16) ushort_t sV[64 * 72];
  __shared__ __align__(16) ushort_t sP[64 * 72];

  const int jt = (bid < 256) ? (15 - (bid >> 5)) : ((bid - 256) >> 5);
  const int c = bid & 31, t = c >> 4, b = (c >> 3) & 1, h = c & 7;

  // stage Q + prefetch kt=0 K/V
  uint4 qq[4], pk[4], pv[2];
#pragma unroll
  for (int i = 0; i < 4; ++i) {
    const int idx = tid + i * 256;
    qq[i] = *(const uint4*)&Qcomb[((size_t)t * ROWS + b * SS + jt * 64 +
                                   (idx >> 4)) * 1024 + h * 128 +
                                  (idx & 15) * 8];
    pk[i] = *(const uint4*)&Kcomb[((size_t)b * SS + (idx >> 4)) * 1024 +
                                  h * 128 + (idx & 15) * 8];
  }
#pragma unroll
  for (int i = 0; i < 2; ++i) {
    const int idx = tid + i * 256;
    pv[i] = *(const uint4*)&vhT[((size_t)b * 512 + h * 64 + (idx >> 3)) * 1024 +
                                (idx & 7) * 8];
  }
#pragma unroll
  for (int i = 0; i < 4; ++i) {
    const int idx = tid + i * 256;
    *(uint4*)&sQ[(idx >> 4) * 136 + (idx & 15) * 8] = qq[i];
  }
  __syncthreads();

  bhalf8 aq[4];
#pragma unroll
  for (int kc = 0; kc < 4; ++kc)
    aq[kc] = *(const bhalf8*)&sQ[(w * 16 + ln) * 136 + kc * 32 + quad * 8];

  f32x4 oacc[4];
#pragma unroll
  for (int ct = 0; ct < 4; ++ct) oacc[ct] = (f32x4){0.f, 0.f, 0.f, 0.f};
  float lsum[4] = {0.f, 0.f, 0.f, 0.f};

  for (int kt = 0; kt <= jt; ++kt) {
    if (kt > 0) __syncthreads();
#pragma unroll
    for (int i = 0; i < 4; ++i) {
      const int idx = tid + i * 256;
      *(uint4*)&sK[(idx >> 4) * 136 + (idx & 15) * 8] = pk[i];
    }
#pragma unroll
    for (int i = 0; i < 2; ++i) {
      const int idx = tid + i * 256;
      *(uint4*)&sV[(idx >> 3) * 72 + (idx & 7) * 8] = pv[i];
    }
    __syncthreads();
    if (kt < jt) {
      const int k1 = (kt + 1) * 64;
#pragma unroll
      for (int i = 0; i < 4; ++i) {
        const int idx = tid + i * 256;
        pk[i] = *(const uint4*)&Kcomb[((size_t)b * SS + k1 + (idx >> 4)) *
                                          1024 + h * 128 + (idx & 15) * 8];
      }
#pragma unroll
      for (int i = 0; i < 2; ++i) {
        const int idx = tid + i * 256;
        pv[i] = *(const uint4*)&vhT[((size_t)b * 512 + h * 64 + (idx >> 3)) *
                                        1024 + k1 + (idx & 7) * 8];
      }
    }

    f32x4 sacc[4];
#pragma unroll
    for (int ct = 0; ct < 4; ++ct) {
      sacc[ct] = (f32x4){0.f, 0.f, 0.f, 0.f};
#pragma unroll
      for (int kc = 0; kc < 4; ++kc) {
        const bhalf8 bk =
            *(const bhalf8*)&sK[(ct * 16 + ln) * 136 + kc * 32 + quad * 8];
        sacc[ct] = __builtin_amdgcn_mfma_f32_16x16x32_bf16(aq[kc], bk,
                                                           sacc[ct], 0, 0, 0);
      }
    }

    const bool diag = (kt == jt);
#pragma unroll
    for (int ct = 0; ct < 4; ++ct)
#pragma unroll
      for (int r = 0; r < 4; ++r) {
        float p;
        if (diag && (ct * 16 + ln > w * 16 + quad * 4 + r))
          p = 0.f;
        else
          p = __expf(sacc[ct][r] * 0.125f - 16.f);
        sacc[ct][r] = p;
        lsum[r] += p;
      }

#pragma unroll
    for (int ct = 0; ct < 4; ++ct)
#pragma unroll
      for (int r = 0; r < 4; ++r)
        sP[(w * 16 + quad * 4 + r) * 72 + ct * 16 + ln] = f2bf(sacc[ct][r]);

#pragma unroll
    for (int kc = 0; kc < 2; ++kc) {
      const bhalf8 ap =
          *(const bhalf8*)&sP[(w * 16 + ln) * 72 + kc * 32 + quad * 8];
#pragma unroll
      for (int ct = 0; ct < 4; ++ct) {
        const bhalf8 bv =
            *(const bhalf8*)&sV[(ct * 16 + ln) * 72 + kc * 32 + quad * 8];
        oacc[ct] = __builtin_amdgcn_mfma_f32_16x16x32_bf16(ap, bv, oacc[ct],
                                                           0, 0, 0);
      }
    }
  }

  // epilogue: normalize, store bf16
#pragma unroll
  for (int r = 0; r < 4; ++r) {
    float s = lsum[r];
    s += __shfl_xor(s, 1);
    s += __shfl_xor(s, 2);
    s += __shfl_xor(s, 4);
    s += __shfl_xor(s, 8);
    const float inv = 1.f / s;
    const int j = jt * 64 + w * 16 + quad * 4 + r;
    const size_t orow = ((size_t)t * ROWS + b * SS + j) * 512 + h * 64;
#pragma unroll
    for (int ct = 0; ct < 4; ++ct)
      attO[orow + ct * 16 + ln] = f2bf(oacc[ct][r] * inv);
  }
}

// ============================================================
// ln: y = resid + attO(bf16, normalized), layernorm
// ============================================================
__global__ __launch_bounds__(64) void ln_kernel(
    const float* __restrict__ u_emb, const float* __restrict__ f_emb,
    const ushort_t* __restrict__ attO, float* __restrict__ out) {
  const int rid = blockIdx.x;
  const int t = rid >> 11, row = rid & 2047;
  const float* resid = t ? f_emb : u_emb;
  const int tid = threadIdx.x;
  const size_t base = (size_t)row * 512;
  const size_t obase = ((size_t)t * ROWS + row) * 512;
  const int o = tid * 8;

  const us8 a = *(const us8*)&attO[obase + o];
  const float4 r0 = *(const float4*)&resid[base + o];
  const float4 r1 = *(const float4*)&resid[base + o + 4];
  float y[8];
  y[0] = r0.x + bf2f((unsigned short)a[0]);
  y[1] = r0.y + bf2f((unsigned short)a[1]);
  y[2] = r0.z + bf2f((unsigned short)a[2]);
  y[3] = r0.w + bf2f((unsigned short)a[3]);
  y[4] = r1.x + bf2f((unsigned short)a[4]);
  y[5] = r1.y + bf2f((unsigned short)a[5]);
  y[6] = r1.z + bf2f((unsigned short)a[6]);
  y[7] = r1.w + bf2f((unsigned short)a[7]);

  float s = 0.f, q = 0.f;
#pragma unroll
  for (int i = 0; i < 8; ++i) {
    s += y[i];
    q += y[i] * y[i];
  }
#pragma unroll
  for (int off = 1; off < 64; off <<= 1) {
    s += __shfl_xor(s, off);
    q += __shfl_xor(q, off);
  }
  const float mean = s * (1.f / 512.f);
  const float var = q * (1.f / 512.f) - mean * mean;
  const float rstd = rsqrtf(var + 1e-5f);

  float4 o0, o1;
  o0.x = (y[0] - mean) * rstd; o0.y = (y[1] - mean) * rstd;
  o0.z = (y[2] - mean) * rstd; o0.w = (y[3] - mean) * rstd;
  o1.x = (y[4] - mean) * rstd; o1.y = (y[5] - mean) * rstd;
  o1.z = (y[6] - mean) * rstd; o1.w = (y[7] - mean) * rstd;
  *(float4*)&out[obase + o] = o0;
  *(float4*)&out[obase + o + 4] = o1;
}

// ============================================================
extern "C" void kernel_launch(void* const* d_in, const int* in_sizes, int n_in,
                              void* d_out, int out_size, void* d_ws,
                              size_t ws_size, hipStream_t stream) {
  (void)in_sizes; (void)n_in; (void)out_size; (void)ws_size;
  const float* u_emb = (const float*)d_in[0];
  const float* f_emb = (const float*)d_in[1];
  const float* gpe = (const float*)d_in[2];
  const float* Wq_w = (const float*)d_in[5];
  const float* Wq_b = (const float*)d_in[6];
  const float* Wkv_w = (const float*)d_in[7];
  const float* Wkv_b = (const float*)d_in[8];
  const float* Wp_w = (const float*)d_in[9];
  const float* Wp_b = (const float*)d_in[10];
  const float* Wu_w = (const float*)d_in[11];
  const float* Wu_b = (const float*)d_in[12];
  const float* Bfc = (const float*)d_in[13];
  const float* Bfp = (const float*)d_in[14];
  const float* Buc = (const float*)d_in[15];
  const float* Bup = (const float*)d_in[16];
  float* out = (float*)d_out;

  ushort_t* ws = (ushort_t*)d_ws;
  const size_t SZ = (size_t)ROWS * EMB;  // 1048576
  ushort_t* Qcomb = ws;                  // 4*SZ
  ushort_t* Kcomb = ws + 4 * SZ;         // 2*SZ
  ushort_t* vhT = ws + 6 * SZ;           // SZ
  ushort_t* attO = ws + 7 * SZ;          // 2*SZ (bf16, normalized)

  dim3 blk(256);
  hipLaunchKernelGGL(projpe_kernel, dim3(40, 16), blk, 0, stream, f_emb, gpe,
                     Wu_w, Wq_w, Wkv_w, Wp_w, Wu_b, Wq_b, Wkv_b, Wp_b, Buc,
                     Bup, Bfc, Bfp, Qcomb, Kcomb, vhT);
  hipLaunchKernelGGL(attn_kernel, dim3(512), blk, 0, stream, Qcomb, Kcomb, vhT,
                     attO);
  hipLaunchKernelGGL(ln_kernel, dim3(4096), dim3(64), 0, stream, u_emb, f_emb,
                     attO, out);
}